// Round 2
// baseline (124.363 us; speedup 1.0000x reference)
//
#include <hip/hip_runtime.h>
#include <hip/hip_bf16.h>

typedef short bf16x8 __attribute__((ext_vector_type(8)));
typedef float f32x4 __attribute__((ext_vector_type(4)));

static constexpr int D = 256;
static constexpr float INV_T = 10.0f;  // 1 / 0.1

__device__ __forceinline__ ushort f2bf(float f) {
  union { float f; unsigned u; } v; v.f = f;
  unsigned r = v.u + 0x7fffu + ((v.u >> 16) & 1u);  // RNE
  return (ushort)(r >> 16);
}

// Kernel 1: L2-normalize rows of images & captions -> bf16; diag logits (fp32).
// One wave per row pair. 4 elements/lane (float4 = 16B coalesced).
__global__ __launch_bounds__(256) void normalize_kernel(
    const float* __restrict__ im, const float* __restrict__ cap,
    ushort* __restrict__ imn, ushort* __restrict__ capn,
    float* __restrict__ diag, int N) {
  int tid = blockIdx.x * 256 + threadIdx.x;
  int w = tid >> 6;            // global wave id == row index
  int lane = threadIdx.x & 63;
  if (w >= N) return;
  float4 vi = ((const float4*)(im + (size_t)w * D))[lane];
  float4 vc = ((const float4*)(cap + (size_t)w * D))[lane];
  float ssi = vi.x*vi.x + vi.y*vi.y + vi.z*vi.z + vi.w*vi.w;
  float ssc = vc.x*vc.x + vc.y*vc.y + vc.z*vc.z + vc.w*vc.w;
  #pragma unroll
  for (int m = 1; m < 64; m <<= 1) {
    ssi += __shfl_xor(ssi, m);
    ssc += __shfl_xor(ssc, m);
  }
  float ri = 1.0f / fmaxf(sqrtf(ssi), 1e-12f);
  float rc = 1.0f / fmaxf(sqrtf(ssc), 1e-12f);
  float ax = vi.x*ri, ay = vi.y*ri, az = vi.z*ri, aw = vi.w*ri;
  float cx = vc.x*rc, cy = vc.y*rc, cz = vc.z*rc, cw = vc.w*rc;
  ushort4 ua, uc;
  ua.x = f2bf(ax); ua.y = f2bf(ay); ua.z = f2bf(az); ua.w = f2bf(aw);
  uc.x = f2bf(cx); uc.y = f2bf(cy); uc.z = f2bf(cz); uc.w = f2bf(cw);
  ((ushort4*)(imn + (size_t)w * D))[lane] = ua;
  ((ushort4*)(capn + (size_t)w * D))[lane] = uc;
  // diagonal logit in fp32 (more accurate than bf16 path)
  float d = ax*cx + ay*cy + az*cz + aw*cw;
  #pragma unroll
  for (int m = 1; m < 64; m <<= 1) d += __shfl_xor(d, m);
  if (lane == 0) diag[w] = d * INV_T;
}

// Kernel 2: S = imn @ capn^T (bf16 MFMA, fp32 acc), fused exp(S/T) and
// row/col partial sums per 128x128 tile. Deterministic: each WAVE owns a
// unique partial slot (bn*2+wn for rows, bm*2+wm for cols) -- no races,
// no atomics.
// Block: 256 threads = 4 waves, each wave owns a 64x64 sub-tile.
__global__ __launch_bounds__(256) void gemm_exp_kernel(
    const ushort* __restrict__ A, const ushort* __restrict__ Bm,
    float* __restrict__ rowpart, float* __restrict__ colpart, int N) {
  constexpr int LDSS = 40;  // 32 + 8 pad (80B row stride -> conflict-free b128)
  __shared__ ushort As[128 * LDSS];
  __shared__ ushort Bs[128 * LDSS];
  int bm = blockIdx.x, bn = blockIdx.y;
  int t = threadIdx.x;
  int lane = t & 63;
  int wv = t >> 6;
  int wm = wv >> 1, wn = wv & 1;
  int srow = t >> 2;           // staging row 0..63 (and +64)
  int scol = (t & 3) * 8;      // staging col offset in bf16 elems (16B chunks)
  const ushort* ag = A + (size_t)bm * 128 * D;
  const ushort* bg = Bm + (size_t)bn * 128 * D;
  f32x4 acc[4][4];
  #pragma unroll
  for (int mi = 0; mi < 4; ++mi)
    #pragma unroll
    for (int ni = 0; ni < 4; ++ni)
      acc[mi][ni] = (f32x4){0.f, 0.f, 0.f, 0.f};

  for (int kk = 0; kk < D / 32; ++kk) {
    uint4 av0 = *(const uint4*)(ag + (size_t)srow * D + kk * 32 + scol);
    uint4 av1 = *(const uint4*)(ag + (size_t)(srow + 64) * D + kk * 32 + scol);
    uint4 bv0 = *(const uint4*)(bg + (size_t)srow * D + kk * 32 + scol);
    uint4 bv1 = *(const uint4*)(bg + (size_t)(srow + 64) * D + kk * 32 + scol);
    __syncthreads();  // previous iter's frag reads done before overwrite
    *(uint4*)(&As[srow * LDSS + scol]) = av0;
    *(uint4*)(&As[(srow + 64) * LDSS + scol]) = av1;
    *(uint4*)(&Bs[srow * LDSS + scol]) = bv0;
    *(uint4*)(&Bs[(srow + 64) * LDSS + scol]) = bv1;
    __syncthreads();
    bf16x8 af[4], bfr[4];
    int rb = lane & 15;
    int kb = (lane >> 4) * 8;
    #pragma unroll
    for (int mi = 0; mi < 4; ++mi)
      af[mi] = *(const bf16x8*)(&As[(wm * 64 + mi * 16 + rb) * LDSS + kb]);
    #pragma unroll
    for (int ni = 0; ni < 4; ++ni)
      bfr[ni] = *(const bf16x8*)(&Bs[(wn * 64 + ni * 16 + rb) * LDSS + kb]);
    #pragma unroll
    for (int mi = 0; mi < 4; ++mi)
      #pragma unroll
      for (int ni = 0; ni < 4; ++ni)
        acc[mi][ni] = __builtin_amdgcn_mfma_f32_16x16x32_bf16(
            af[mi], bfr[ni], acc[mi][ni], 0, 0, 0);
  }

  // exp(logits) in place; logits bounded in [-10,10] -> no max subtraction
  #pragma unroll
  for (int mi = 0; mi < 4; ++mi)
    #pragma unroll
    for (int ni = 0; ni < 4; ++ni)
      #pragma unroll
      for (int r = 0; r < 4; ++r)
        acc[mi][ni][r] = __expf(acc[mi][ni][r] * INV_T);

  // C/D layout (m89-verified): row = (lane>>4)*4 + r, col = lane&15
  // row partial sums over THIS WAVE's 64 columns -> slot (bn*2 + wn)
  #pragma unroll
  for (int mi = 0; mi < 4; ++mi)
    #pragma unroll
    for (int r = 0; r < 4; ++r) {
      float v = acc[mi][0][r] + acc[mi][1][r] + acc[mi][2][r] + acc[mi][3][r];
      v += __shfl_xor(v, 1); v += __shfl_xor(v, 2);
      v += __shfl_xor(v, 4); v += __shfl_xor(v, 8);
      if ((lane & 15) == 0)
        rowpart[(size_t)(bn * 2 + wn) * N + bm * 128 + wm * 64 + mi * 16 + (lane >> 4) * 4 + r] = v;
    }
  // col partial sums over THIS WAVE's 64 rows -> slot (bm*2 + wm)
  #pragma unroll
  for (int ni = 0; ni < 4; ++ni) {
    float v = 0.f;
    #pragma unroll
    for (int mi = 0; mi < 4; ++mi)
      #pragma unroll
      for (int r = 0; r < 4; ++r)
        v += acc[mi][ni][r];
    v += __shfl_xor(v, 16); v += __shfl_xor(v, 32);
    if (lane < 16)
      colpart[(size_t)(bm * 2 + wm) * N + bn * 128 + wn * 64 + ni * 16 + lane] = v;
  }
}

// Kernel 3: per-index reduction of partials -> per-sample loss
__global__ __launch_bounds__(256) void reduce_kernel(
    const float* __restrict__ rowpart, const float* __restrict__ colpart,
    const float* __restrict__ diag, float* __restrict__ lossbuf, int N, int NP) {
  int i = blockIdx.x * 256 + threadIdx.x;
  if (i >= N) return;
  float rs = 0.f, cs = 0.f;
  for (int b = 0; b < NP; ++b) {
    rs += rowpart[(size_t)b * N + i];
    cs += colpart[(size_t)b * N + i];
  }
  lossbuf[i] = logf(rs) + logf(cs) - 2.0f * diag[i];
}

// Kernel 4: final mean
__global__ __launch_bounds__(256) void final_kernel(
    const float* __restrict__ lossbuf, float* __restrict__ out, int N) {
  __shared__ float red[4];
  float s = 0.f;
  for (int i = threadIdx.x; i < N; i += 256) s += lossbuf[i];
  #pragma unroll
  for (int m = 1; m < 64; m <<= 1) s += __shfl_xor(s, m);
  if ((threadIdx.x & 63) == 0) red[threadIdx.x >> 6] = s;
  __syncthreads();
  if (threadIdx.x == 0)
    out[0] = (red[0] + red[1] + red[2] + red[3]) * (0.5f / (float)N);
}

extern "C" void kernel_launch(void* const* d_in, const int* in_sizes, int n_in,
                              void* d_out, int out_size, void* d_ws, size_t ws_size,
                              hipStream_t stream) {
  const float* images = (const float*)d_in[0];
  const float* captions = (const float*)d_in[1];
  int N = in_sizes[0] / D;   // 8192
  int NB = N / 128;          // 64 tile-blocks per dim
  int NP = NB * 2;           // 128 per-wave partial slots per sample
  char* w = (char*)d_ws;
  size_t off = 0;
  ushort* imn  = (ushort*)(w + off); off += (size_t)N * D * 2;
  ushort* capn = (ushort*)(w + off); off += (size_t)N * D * 2;
  float* diag    = (float*)(w + off); off += (size_t)N * 4;
  float* rowpart = (float*)(w + off); off += (size_t)NP * N * 4;
  float* colpart = (float*)(w + off); off += (size_t)NP * N * 4;
  float* lossbuf = (float*)(w + off); off += (size_t)N * 4;
  float* out = (float*)d_out;

  normalize_kernel<<<N / 4, 256, 0, stream>>>(images, captions, imn, capn, diag, N);
  dim3 g(NB, NB);
  gemm_exp_kernel<<<g, 256, 0, stream>>>(imn, capn, rowpart, colpart, N);
  reduce_kernel<<<(N + 255) / 256, 256, 0, stream>>>(rowpart, colpart, diag, lossbuf, N, NP);
  final_kernel<<<1, 256, 0, stream>>>(lossbuf, out, N);
}

// Round 3
// 102.008 us; speedup vs baseline: 1.2192x; 1.2192x over previous
//
#include <hip/hip_runtime.h>
#include <hip/hip_bf16.h>

typedef short bf16x8 __attribute__((ext_vector_type(8)));
typedef float f32x4 __attribute__((ext_vector_type(4)));

typedef __attribute__((address_space(3))) void as3_void;
typedef const __attribute__((address_space(1))) void as1_void;

static constexpr int D = 256;
static constexpr float INV_T = 10.0f;  // 1 / 0.1

__device__ __forceinline__ ushort f2bf(float f) {
  union { float f; unsigned u; } v; v.f = f;
  unsigned r = v.u + 0x7fffu + ((v.u >> 16) & 1u);  // RNE
  return (ushort)(r >> 16);
}

// Kernel 1: L2-normalize rows of images & captions -> bf16; diag logits (fp32).
__global__ __launch_bounds__(256) void normalize_kernel(
    const float* __restrict__ im, const float* __restrict__ cap,
    ushort* __restrict__ imn, ushort* __restrict__ capn,
    float* __restrict__ diag, int N) {
  int tid = blockIdx.x * 256 + threadIdx.x;
  int w = tid >> 6;            // global wave id == row index
  int lane = threadIdx.x & 63;
  if (w >= N) return;
  float4 vi = ((const float4*)(im + (size_t)w * D))[lane];
  float4 vc = ((const float4*)(cap + (size_t)w * D))[lane];
  float ssi = vi.x*vi.x + vi.y*vi.y + vi.z*vi.z + vi.w*vi.w;
  float ssc = vc.x*vc.x + vc.y*vc.y + vc.z*vc.z + vc.w*vc.w;
  #pragma unroll
  for (int m = 1; m < 64; m <<= 1) {
    ssi += __shfl_xor(ssi, m);
    ssc += __shfl_xor(ssc, m);
  }
  float ri = 1.0f / fmaxf(sqrtf(ssi), 1e-12f);
  float rc = 1.0f / fmaxf(sqrtf(ssc), 1e-12f);
  float ax = vi.x*ri, ay = vi.y*ri, az = vi.z*ri, aw = vi.w*ri;
  float cx = vc.x*rc, cy = vc.y*rc, cz = vc.z*rc, cw = vc.w*rc;
  ushort4 ua, uc;
  ua.x = f2bf(ax); ua.y = f2bf(ay); ua.z = f2bf(az); ua.w = f2bf(aw);
  uc.x = f2bf(cx); uc.y = f2bf(cy); uc.z = f2bf(cz); uc.w = f2bf(cw);
  ((ushort4*)(imn + (size_t)w * D))[lane] = ua;
  ((ushort4*)(capn + (size_t)w * D))[lane] = uc;
  float d = ax*cx + ay*cy + az*cz + aw*cw;
  #pragma unroll
  for (int m = 1; m < 64; m <<= 1) d += __shfl_xor(d, m);
  if (lane == 0) diag[w] = d * INV_T;
}

// Kernel 2: S = imn @ capn^T (bf16 MFMA), fused exp(S/T) + row/col partial
// sums. m97 structure: linear [128][32] LDS per operand, global_load_lds
// width=16 staging, 2-barrier K-loop. Each wave owns a unique partial slot.
__global__ __launch_bounds__(256) void gemm_exp_kernel(
    const ushort* __restrict__ A, const ushort* __restrict__ Bm,
    float* __restrict__ rowpart, float* __restrict__ colpart, int N) {
  __shared__ ushort As[128 * 32];  // 8 KB, linear (global_load_lds needs it)
  __shared__ ushort Bs[128 * 32];
  int bm = blockIdx.x, bn = blockIdx.y;
  int t = threadIdx.x;
  int lane = t & 63;
  int wv = t >> 6;
  int wm = wv >> 1, wn = wv & 1;
  // staging geometry: chunk = 1024 B = 16 rows x 32 elems; wave wv owns
  // chunks {2wv, 2wv+1} of each operand. LDS write addr = base + lane*16,
  // i.e. row = 16c + (lane>>2), col elem = (lane&3)*8 -- matched on the
  // global side below (both linear: rule-21 both-sides-or-neither).
  int c0 = wv * 2;
  int lrow = lane >> 2;
  int lcol = (lane & 3) * 8;
  const ushort* agbase = A + (size_t)bm * 128 * D + (size_t)(c0 * 16 + lrow) * D + lcol;
  const ushort* bgbase = Bm + (size_t)bn * 128 * D + (size_t)(c0 * 16 + lrow) * D + lcol;

  f32x4 acc[4][4];
  #pragma unroll
  for (int mi = 0; mi < 4; ++mi)
    #pragma unroll
    for (int ni = 0; ni < 4; ++ni)
      acc[mi][ni] = (f32x4){0.f, 0.f, 0.f, 0.f};

  int rb = lane & 15;
  int kb = (lane >> 4) * 8;

  for (int kk = 0; kk < D / 32; ++kk) {
    const ushort* ga = agbase + kk * 32;
    const ushort* gb = bgbase + kk * 32;
    __builtin_amdgcn_global_load_lds((as1_void*)(ga),
        (as3_void*)(&As[c0 * 512]), 16, 0, 0);
    __builtin_amdgcn_global_load_lds((as1_void*)(ga + 16 * D),
        (as3_void*)(&As[c0 * 512 + 512]), 16, 0, 0);
    __builtin_amdgcn_global_load_lds((as1_void*)(gb),
        (as3_void*)(&Bs[c0 * 512]), 16, 0, 0);
    __builtin_amdgcn_global_load_lds((as1_void*)(gb + 16 * D),
        (as3_void*)(&Bs[c0 * 512 + 512]), 16, 0, 0);
    __syncthreads();  // drains vmcnt -> staged tile visible
    bf16x8 af[4], bfr[4];
    #pragma unroll
    for (int mi = 0; mi < 4; ++mi)
      af[mi] = *(const bf16x8*)(&As[(wm * 64 + mi * 16 + rb) * 32 + kb]);
    #pragma unroll
    for (int ni = 0; ni < 4; ++ni)
      bfr[ni] = *(const bf16x8*)(&Bs[(wn * 64 + ni * 16 + rb) * 32 + kb]);
    #pragma unroll
    for (int mi = 0; mi < 4; ++mi)
      #pragma unroll
      for (int ni = 0; ni < 4; ++ni)
        acc[mi][ni] = __builtin_amdgcn_mfma_f32_16x16x32_bf16(
            af[mi], bfr[ni], acc[mi][ni], 0, 0, 0);
    __syncthreads();  // all frag reads done before next-iter overwrite
  }

  // exp(logits); logits in [-10,10] -> no max subtraction needed in fp32
  #pragma unroll
  for (int mi = 0; mi < 4; ++mi)
    #pragma unroll
    for (int ni = 0; ni < 4; ++ni)
      #pragma unroll
      for (int r = 0; r < 4; ++r)
        acc[mi][ni][r] = __expf(acc[mi][ni][r] * INV_T);

  // C/D layout: row = (lane>>4)*4 + r, col = lane&15
  // row partial sums over this wave's 64 columns -> slot (bn*2 + wn)
  #pragma unroll
  for (int mi = 0; mi < 4; ++mi)
    #pragma unroll
    for (int r = 0; r < 4; ++r) {
      float v = acc[mi][0][r] + acc[mi][1][r] + acc[mi][2][r] + acc[mi][3][r];
      v += __shfl_xor(v, 1); v += __shfl_xor(v, 2);
      v += __shfl_xor(v, 4); v += __shfl_xor(v, 8);
      if ((lane & 15) == 0)
        rowpart[(size_t)(bn * 2 + wn) * N + bm * 128 + wm * 64 + mi * 16 + (lane >> 4) * 4 + r] = v;
    }
  // col partial sums over this wave's 64 rows -> slot (bm*2 + wm)
  #pragma unroll
  for (int ni = 0; ni < 4; ++ni) {
    float v = 0.f;
    #pragma unroll
    for (int mi = 0; mi < 4; ++mi)
      #pragma unroll
      for (int r = 0; r < 4; ++r)
        v += acc[mi][ni][r];
    v += __shfl_xor(v, 16); v += __shfl_xor(v, 32);
    if (lane < 16)
      colpart[(size_t)(bm * 2 + wm) * N + bn * 128 + wn * 64 + ni * 16 + lane] = v;
  }
}

// Kernel 3: per-index reduction of partials -> per-sample loss + block sums
__global__ __launch_bounds__(256) void reduce_kernel(
    const float* __restrict__ rowpart, const float* __restrict__ colpart,
    const float* __restrict__ diag, float* __restrict__ blocksum, int N, int NP) {
  __shared__ float red[4];
  int i = blockIdx.x * 256 + threadIdx.x;
  float rs = 0.f, cs = 0.f;
  for (int b = 0; b < NP; ++b) {
    rs += rowpart[(size_t)b * N + i];
    cs += colpart[(size_t)b * N + i];
  }
  float l = logf(rs) + logf(cs) - 2.0f * diag[i];
  #pragma unroll
  for (int m = 1; m < 64; m <<= 1) l += __shfl_xor(l, m);
  if ((threadIdx.x & 63) == 0) red[threadIdx.x >> 6] = l;
  __syncthreads();
  if (threadIdx.x == 0)
    blocksum[blockIdx.x] = red[0] + red[1] + red[2] + red[3];
}

// Kernel 4: final mean over 32 block sums
__global__ __launch_bounds__(64) void final_kernel(
    const float* __restrict__ blocksum, float* __restrict__ out, int N, int NBLK) {
  float s = (threadIdx.x < NBLK) ? blocksum[threadIdx.x] : 0.f;
  #pragma unroll
  for (int m = 1; m < 64; m <<= 1) s += __shfl_xor(s, m);
  if (threadIdx.x == 0) out[0] = s * (0.5f / (float)N);
}

extern "C" void kernel_launch(void* const* d_in, const int* in_sizes, int n_in,
                              void* d_out, int out_size, void* d_ws, size_t ws_size,
                              hipStream_t stream) {
  const float* images = (const float*)d_in[0];
  const float* captions = (const float*)d_in[1];
  int N = in_sizes[0] / D;   // 8192
  int NB = N / 128;          // 64 tile-blocks per dim
  int NP = NB * 2;           // 128 per-wave partial slots per sample
  int NBLK = N / 256;        // 32 reduce blocks
  char* w = (char*)d_ws;
  size_t off = 0;
  ushort* imn  = (ushort*)(w + off); off += (size_t)N * D * 2;
  ushort* capn = (ushort*)(w + off); off += (size_t)N * D * 2;
  float* diag    = (float*)(w + off); off += (size_t)N * 4;
  float* rowpart = (float*)(w + off); off += (size_t)NP * N * 4;
  float* colpart = (float*)(w + off); off += (size_t)NP * N * 4;
  float* blocksum = (float*)(w + off); off += (size_t)NBLK * 4;
  float* out = (float*)d_out;

  normalize_kernel<<<N / 4, 256, 0, stream>>>(images, captions, imn, capn, diag, N);
  dim3 g(NB, NB);
  gemm_exp_kernel<<<g, 256, 0, stream>>>(imn, capn, rowpart, colpart, N);
  reduce_kernel<<<NBLK, 256, 0, stream>>>(rowpart, colpart, diag, blocksum, N, NP);
  final_kernel<<<1, 64, 0, stream>>>(blocksum, out, N, NBLK);
}

// Round 4
// 88.595 us; speedup vs baseline: 1.4037x; 1.1514x over previous
//
#include <hip/hip_runtime.h>
#include <hip/hip_bf16.h>

typedef short bf16x8 __attribute__((ext_vector_type(8)));
typedef float f32x4 __attribute__((ext_vector_type(4)));

typedef __attribute__((address_space(3))) void as3_void;
typedef const __attribute__((address_space(1))) void as1_void;

static constexpr int D = 256;
static constexpr float INV_T = 10.0f;  // 1 / 0.1

__device__ __forceinline__ ushort f2bf(float f) {
  union { float f; unsigned u; } v; v.f = f;
  unsigned r = v.u + 0x7fffu + ((v.u >> 16) & 1u);  // RNE
  return (ushort)(r >> 16);
}

// Kernel 1: L2-normalize rows of images & captions -> bf16; diag logits (fp32).
__global__ __launch_bounds__(256) void normalize_kernel(
    const float* __restrict__ im, const float* __restrict__ cap,
    ushort* __restrict__ imn, ushort* __restrict__ capn,
    float* __restrict__ diag, int N) {
  int tid = blockIdx.x * 256 + threadIdx.x;
  int w = tid >> 6;
  int lane = threadIdx.x & 63;
  if (w >= N) return;
  float4 vi = ((const float4*)(im + (size_t)w * D))[lane];
  float4 vc = ((const float4*)(cap + (size_t)w * D))[lane];
  float ssi = vi.x*vi.x + vi.y*vi.y + vi.z*vi.z + vi.w*vi.w;
  float ssc = vc.x*vc.x + vc.y*vc.y + vc.z*vc.z + vc.w*vc.w;
  #pragma unroll
  for (int m = 1; m < 64; m <<= 1) {
    ssi += __shfl_xor(ssi, m);
    ssc += __shfl_xor(ssc, m);
  }
  float ri = 1.0f / fmaxf(sqrtf(ssi), 1e-12f);
  float rc = 1.0f / fmaxf(sqrtf(ssc), 1e-12f);
  float ax = vi.x*ri, ay = vi.y*ri, az = vi.z*ri, aw = vi.w*ri;
  float cx = vc.x*rc, cy = vc.y*rc, cz = vc.z*rc, cw = vc.w*rc;
  ushort4 ua, uc;
  ua.x = f2bf(ax); ua.y = f2bf(ay); ua.z = f2bf(az); ua.w = f2bf(aw);
  uc.x = f2bf(cx); uc.y = f2bf(cy); uc.z = f2bf(cz); uc.w = f2bf(cw);
  ((ushort4*)(imn + (size_t)w * D))[lane] = ua;
  ((ushort4*)(capn + (size_t)w * D))[lane] = uc;
  float d = ax*cx + ay*cy + az*cz + aw*cw;
  #pragma unroll
  for (int m = 1; m < 64; m <<= 1) d += __shfl_xor(d, m);
  if (lane == 0) diag[w] = d * INV_T;
}

// Kernel 2: 256x256 tile, 8 waves (2M x 4N), BK=64, double-buffered linear LDS,
// global_load_lds width=16 staging, T3-minimum 2-phase schedule (stage-next
// issued before compute-current; one __syncthreads per K-tile).
// Fused exp(S/T) + row/col partial sums; each wave owns unique partial slots.
__global__ __launch_bounds__(512, 2) void gemm_exp_kernel(
    const ushort* __restrict__ A, const ushort* __restrict__ Bm,
    float* __restrict__ rowpart, float* __restrict__ colpart, int N) {
  __shared__ ushort As[2][256 * 64];  // 2 x 32 KB
  __shared__ ushort Bs[2][256 * 64];  // 2 x 32 KB   (total 128 KB)
  int bm = blockIdx.x, bn = blockIdx.y;
  int t = threadIdx.x;
  int lane = t & 63;
  int wv = t >> 6;             // 0..7
  int wm = wv >> 2;            // 0..1 : rows [wm*128, +128)
  int wn = wv & 3;             // 0..3 : cols [wn*64, +64)

  // staging geometry: per buffer, operand = 256x64 elems = 32KB = 4 rounds of
  // 512 lanes x 16B. Lane's chunk c = q*512 + wv*64 + lane ->
  // row = q*64 + wv*8 + (lane>>3), colelem = (lane&7)*8. LDS dest is linear
  // (wave-uniform base + lane*16) matching the same (row,col) -> rule 21 ok.
  int srow = wv * 8 + (lane >> 3);
  int scol = (lane & 7) * 8;
  const ushort* agbase = A + ((size_t)bm * 256 + srow) * D + scol;
  const ushort* bgbase = Bm + ((size_t)bn * 256 + srow) * D + scol;

  f32x4 acc[8][4];
  #pragma unroll
  for (int mi = 0; mi < 8; ++mi)
    #pragma unroll
    for (int ni = 0; ni < 4; ++ni)
      acc[mi][ni] = (f32x4){0.f, 0.f, 0.f, 0.f};

  int rb = lane & 15;
  int kb = (lane >> 4) * 8;

#define STAGE(buf, kt)                                                        \
  {                                                                           \
    _Pragma("unroll")                                                         \
    for (int q = 0; q < 4; ++q) {                                             \
      __builtin_amdgcn_global_load_lds(                                       \
          (as1_void*)(agbase + (size_t)q * 64 * D + (kt) * 64),               \
          (as3_void*)(&As[buf][q * 4096 + wv * 512]), 16, 0, 0);              \
      __builtin_amdgcn_global_load_lds(                                       \
          (as1_void*)(bgbase + (size_t)q * 64 * D + (kt) * 64),               \
          (as3_void*)(&Bs[buf][q * 4096 + wv * 512]), 16, 0, 0);              \
    }                                                                         \
  }

  STAGE(0, 0);
  __syncthreads();

  #pragma unroll
  for (int kt = 0; kt < 4; ++kt) {
    int cur = kt & 1;
    if (kt < 3) STAGE(cur ^ 1, kt + 1);
    #pragma unroll
    for (int ks = 0; ks < 2; ++ks) {
      bf16x8 af[8], bfr[4];
      #pragma unroll
      for (int mi = 0; mi < 8; ++mi)
        af[mi] = *(const bf16x8*)(&As[cur][(wm * 128 + mi * 16 + rb) * 64 + ks * 32 + kb]);
      #pragma unroll
      for (int ni = 0; ni < 4; ++ni)
        bfr[ni] = *(const bf16x8*)(&Bs[cur][(wn * 64 + ni * 16 + rb) * 64 + ks * 32 + kb]);
      #pragma unroll
      for (int mi = 0; mi < 8; ++mi)
        #pragma unroll
        for (int ni = 0; ni < 4; ++ni)
          acc[mi][ni] = __builtin_amdgcn_mfma_f32_16x16x32_bf16(
              af[mi], bfr[ni], acc[mi][ni], 0, 0, 0);
    }
    if (kt < 3) __syncthreads();
  }
#undef STAGE

  // exp(logits); logits in [-10,10] -> safe without max subtraction
  #pragma unroll
  for (int mi = 0; mi < 8; ++mi)
    #pragma unroll
    for (int ni = 0; ni < 4; ++ni)
      #pragma unroll
      for (int r = 0; r < 4; ++r)
        acc[mi][ni][r] = __expf(acc[mi][ni][r] * INV_T);

  // C/D layout: col = lane&15, row = (lane>>4)*4 + r
  // row partial sums over this wave's 64 cols -> slot (bn*4 + wn)
  #pragma unroll
  for (int mi = 0; mi < 8; ++mi)
    #pragma unroll
    for (int r = 0; r < 4; ++r) {
      float v = acc[mi][0][r] + acc[mi][1][r] + acc[mi][2][r] + acc[mi][3][r];
      v += __shfl_xor(v, 1); v += __shfl_xor(v, 2);
      v += __shfl_xor(v, 4); v += __shfl_xor(v, 8);
      if ((lane & 15) == 0)
        rowpart[(size_t)(bn * 4 + wn) * N + bm * 256 + wm * 128 + mi * 16 + (lane >> 4) * 4 + r] = v;
    }
  // col partial sums over this wave's 128 rows -> slot (bm*2 + wm)
  #pragma unroll
  for (int ni = 0; ni < 4; ++ni) {
    float v = 0.f;
    #pragma unroll
    for (int mi = 0; mi < 8; ++mi)
      #pragma unroll
      for (int r = 0; r < 4; ++r)
        v += acc[mi][ni][r];
    v += __shfl_xor(v, 16); v += __shfl_xor(v, 32);
    if (lane < 16)
      colpart[(size_t)(bm * 2 + wm) * N + bn * 256 + wn * 64 + ni * 16 + lane] = v;
  }
}

// Kernel 3: coalesced partial reduction. 128 blocks x 256 threads; wave w
// owns slot residues w, w+4, ... (contiguous 256B rows per load); cross-wave
// combine in LDS; wave 0 computes per-sample loss and the block sum.
__global__ __launch_bounds__(256) void reduce_kernel(
    const float* __restrict__ rowpart, const float* __restrict__ colpart,
    const float* __restrict__ diag, float* __restrict__ blocksum,
    int N, int NPr, int NPc) {
  __shared__ float redr[4][64], redc[4][64];
  int w = threadIdx.x >> 6, s = threadIdx.x & 63;
  int i = blockIdx.x * 64 + s;
  float rs = 0.f, cs = 0.f;
  for (int k = w; k < NPr; k += 4) rs += rowpart[(size_t)k * N + i];
  for (int k = w; k < NPc; k += 4) cs += colpart[(size_t)k * N + i];
  redr[w][s] = rs; redc[w][s] = cs;
  __syncthreads();
  if (w == 0) {
    float R = redr[0][s] + redr[1][s] + redr[2][s] + redr[3][s];
    float C = redc[0][s] + redc[1][s] + redc[2][s] + redc[3][s];
    float l = logf(R) + logf(C) - 2.0f * diag[i];
    #pragma unroll
    for (int m = 1; m < 64; m <<= 1) l += __shfl_xor(l, m);
    if (s == 0) blocksum[blockIdx.x] = l;
  }
}

// Kernel 4: final mean over 128 block sums
__global__ __launch_bounds__(128) void final_kernel(
    const float* __restrict__ blocksum, float* __restrict__ out, int N) {
  __shared__ float red[2];
  float v = blocksum[threadIdx.x];
  #pragma unroll
  for (int m = 1; m < 64; m <<= 1) v += __shfl_xor(v, m);
  if ((threadIdx.x & 63) == 0) red[threadIdx.x >> 6] = v;
  __syncthreads();
  if (threadIdx.x == 0) out[0] = (red[0] + red[1]) * (0.5f / (float)N);
}

extern "C" void kernel_launch(void* const* d_in, const int* in_sizes, int n_in,
                              void* d_out, int out_size, void* d_ws, size_t ws_size,
                              hipStream_t stream) {
  const float* images = (const float*)d_in[0];
  const float* captions = (const float*)d_in[1];
  int N = in_sizes[0] / D;   // 8192
  int NB = N / 256;          // 32 tile-blocks per dim
  int NPr = NB * 4;          // 128 row-partial slots
  int NPc = NB * 2;          // 64 col-partial slots
  char* w = (char*)d_ws;
  size_t off = 0;
  ushort* imn  = (ushort*)(w + off); off += (size_t)N * D * 2;
  ushort* capn = (ushort*)(w + off); off += (size_t)N * D * 2;
  float* diag    = (float*)(w + off); off += (size_t)N * 4;
  float* rowpart = (float*)(w + off); off += (size_t)NPr * N * 4;
  float* colpart = (float*)(w + off); off += (size_t)NPc * N * 4;
  float* blocksum = (float*)(w + off); off += 1024;
  float* out = (float*)d_out;

  normalize_kernel<<<N / 4, 256, 0, stream>>>(images, captions, imn, capn, diag, N);
  dim3 g(NB, NB);
  gemm_exp_kernel<<<g, 512, 0, stream>>>(imn, capn, rowpart, colpart, N);
  reduce_kernel<<<N / 64, 256, 0, stream>>>(rowpart, colpart, diag, blocksum, N, NPr, NPc);
  final_kernel<<<1, 128, 0, stream>>>(blocksum, out, N);
}

// Round 5
// 79.176 us; speedup vs baseline: 1.5707x; 1.1190x over previous
//
#include <hip/hip_runtime.h>
#include <hip/hip_bf16.h>

typedef short bf16x8 __attribute__((ext_vector_type(8)));
typedef float f32x4 __attribute__((ext_vector_type(4)));

typedef __attribute__((address_space(3))) void as3_void;
typedef const __attribute__((address_space(1))) void as1_void;

static constexpr int D = 256;
static constexpr float INV_T = 10.0f;  // 1 / 0.1

__device__ __forceinline__ ushort f2bf(float f) {
  union { float f; unsigned u; } v; v.f = f;
  unsigned r = v.u + 0x7fffu + ((v.u >> 16) & 1u);  // RNE
  return (ushort)(r >> 16);
}

// Kernel 1: L2-normalize rows of images & captions -> bf16; diag logits (fp32).
__global__ __launch_bounds__(256) void normalize_kernel(
    const float* __restrict__ im, const float* __restrict__ cap,
    ushort* __restrict__ imn, ushort* __restrict__ capn,
    float* __restrict__ diag, int N) {
  int tid = blockIdx.x * 256 + threadIdx.x;
  int w = tid >> 6;
  int lane = threadIdx.x & 63;
  if (w >= N) return;
  float4 vi = ((const float4*)(im + (size_t)w * D))[lane];
  float4 vc = ((const float4*)(cap + (size_t)w * D))[lane];
  float ssi = vi.x*vi.x + vi.y*vi.y + vi.z*vi.z + vi.w*vi.w;
  float ssc = vc.x*vc.x + vc.y*vc.y + vc.z*vc.z + vc.w*vc.w;
  #pragma unroll
  for (int m = 1; m < 64; m <<= 1) {
    ssi += __shfl_xor(ssi, m);
    ssc += __shfl_xor(ssc, m);
  }
  float ri = 1.0f / fmaxf(sqrtf(ssi), 1e-12f);
  float rc = 1.0f / fmaxf(sqrtf(ssc), 1e-12f);
  float ax = vi.x*ri, ay = vi.y*ri, az = vi.z*ri, aw = vi.w*ri;
  float cx = vc.x*rc, cy = vc.y*rc, cz = vc.z*rc, cw = vc.w*rc;
  ushort4 ua, uc;
  ua.x = f2bf(ax); ua.y = f2bf(ay); ua.z = f2bf(az); ua.w = f2bf(aw);
  uc.x = f2bf(cx); uc.y = f2bf(cy); uc.z = f2bf(cz); uc.w = f2bf(cw);
  ((ushort4*)(imn + (size_t)w * D))[lane] = ua;
  ((ushort4*)(capn + (size_t)w * D))[lane] = uc;
  float d = ax*cx + ay*cy + az*cz + aw*cw;
  #pragma unroll
  for (int m = 1; m < 64; m <<= 1) d += __shfl_xor(d, m);
  if (lane == 0) diag[w] = d * INV_T;
}

// Kernel 2: 256x256 tile, 8 waves (2M x 4N), BK=64, double-buffered LDS,
// global_load_lds staging with PRE-SWIZZLED global source (rule 21:
// linear LDS dest + same XOR involution on the ds_read side), counted-vmcnt
// raw-barrier schedule (never drain to 0 mid-loop), setprio around MFMA.
// Swizzle: lds slot (row, c') holds global (row, c' ^ ((row&7)*16B)).
__global__ __launch_bounds__(512, 2) void gemm_exp_kernel(
    const ushort* __restrict__ A, const ushort* __restrict__ Bm,
    float* __restrict__ rowpart, float* __restrict__ colpart, int N) {
  __shared__ ushort As[2][256 * 64];  // 2 x 32 KB
  __shared__ ushort Bs[2][256 * 64];  // 2 x 32 KB  (128 KB total)
  int bm = blockIdx.x, bn = blockIdx.y;
  int t = threadIdx.x;
  int lane = t & 63;
  int wv = t >> 6;             // 0..7
  int wm = wv >> 2;            // 0..1 : rows [wm*128, +128)
  int wn = wv & 3;             // 0..3 : cols [wn*64, +64)

  // Staging: per q-round, lane writes LDS linear slot row=q*64+wv*8+(lane>>3),
  // col' = (lane&7)*8. Source col is pre-swizzled: col = col' ^ ((lane>>3)*8)
  // (row&7 == lane>>3 since wv*8 is 0 mod 8).
  int srow = wv * 8 + (lane >> 3);
  int scol = (((lane & 7) ^ (lane >> 3)) * 8);
  const ushort* agbase = A + ((size_t)bm * 256 + srow) * D + scol;
  const ushort* bgbase = Bm + ((size_t)bn * 256 + srow) * D + scol;

  f32x4 acc[8][4];
  #pragma unroll
  for (int mi = 0; mi < 8; ++mi)
    #pragma unroll
    for (int ni = 0; ni < 4; ++ni)
      acc[mi][ni] = (f32x4){0.f, 0.f, 0.f, 0.f};

  int rb = lane & 15;
  int kb = (lane >> 4) * 8;
  int rb7s = (rb & 7) * 8;     // read-side swizzle term (elem units)

#define STAGE(buf, kt)                                                        \
  {                                                                           \
    _Pragma("unroll")                                                         \
    for (int q = 0; q < 4; ++q) {                                             \
      __builtin_amdgcn_global_load_lds(                                       \
          (as1_void*)(agbase + (size_t)q * 64 * D + (kt) * 64),               \
          (as3_void*)(&As[buf][q * 4096 + wv * 512]), 16, 0, 0);              \
      __builtin_amdgcn_global_load_lds(                                       \
          (as1_void*)(bgbase + (size_t)q * 64 * D + (kt) * 64),               \
          (as3_void*)(&Bs[buf][q * 4096 + wv * 512]), 16, 0, 0);              \
    }                                                                         \
  }
#define WAITVM(n) asm volatile("s_waitcnt vmcnt(" #n ")" ::: "memory")
#define WAITLGKM0() asm volatile("s_waitcnt lgkmcnt(0)" ::: "memory")
#define BAR() __builtin_amdgcn_s_barrier()
#define CFENCE() asm volatile("" ::: "memory")

  // frag loads for one (cur, ks): 8 A + 4 B b128 reads, swizzled column
#define LOADFRAGS(AF, BF, cur, ks)                                            \
  {                                                                           \
    int cc = ((ks) * 32 + kb) ^ rb7s;                                         \
    _Pragma("unroll")                                                         \
    for (int mi = 0; mi < 8; ++mi)                                            \
      AF[mi] = *(const bf16x8*)(&As[cur][(wm * 128 + mi * 16 + rb) * 64 + cc]); \
    _Pragma("unroll")                                                         \
    for (int ni = 0; ni < 4; ++ni)                                            \
      BF[ni] = *(const bf16x8*)(&Bs[cur][(wn * 64 + ni * 16 + rb) * 64 + cc]); \
  }
#define MFMAS(AF, BF)                                                         \
  {                                                                           \
    __builtin_amdgcn_s_setprio(1);                                            \
    _Pragma("unroll")                                                         \
    for (int mi = 0; mi < 8; ++mi)                                            \
      _Pragma("unroll")                                                       \
      for (int ni = 0; ni < 4; ++ni)                                          \
        acc[mi][ni] = __builtin_amdgcn_mfma_f32_16x16x32_bf16(                \
            AF[mi], BF[ni], acc[mi][ni], 0, 0, 0);                            \
    __builtin_amdgcn_s_setprio(0);                                            \
  }

  // Prologue: stage K-tiles 0 and 1 (8 loads each -> 16 outstanding)
  STAGE(0, 0);
  CFENCE();
  STAGE(1, 1);
  CFENCE();

  {  // kt = 0 (cur=0), restage kt=2 -> buf0
    WAITVM(8); BAR();
    bf16x8 af0[8], bf0[4], af1[8], bf1[4];
    LOADFRAGS(af0, bf0, 0, 0);
    MFMAS(af0, bf0);
    LOADFRAGS(af1, bf1, 0, 1);
    WAITLGKM0();
    __builtin_amdgcn_sched_barrier(0);
    BAR();                      // all waves done reading buf0
    STAGE(0, 2);
    CFENCE();
    MFMAS(af1, bf1);
  }
  {  // kt = 1 (cur=1), restage kt=3 -> buf1
    WAITVM(8); BAR();
    bf16x8 af0[8], bf0[4], af1[8], bf1[4];
    LOADFRAGS(af0, bf0, 1, 0);
    MFMAS(af0, bf0);
    LOADFRAGS(af1, bf1, 1, 1);
    WAITLGKM0();
    __builtin_amdgcn_sched_barrier(0);
    BAR();                      // all waves done reading buf1
    STAGE(1, 3);
    CFENCE();
    MFMAS(af1, bf1);
  }
  {  // kt = 2 (cur=0), no stage
    WAITVM(8); BAR();
    bf16x8 af0[8], bf0[4], af1[8], bf1[4];
    LOADFRAGS(af0, bf0, 0, 0);
    MFMAS(af0, bf0);
    LOADFRAGS(af1, bf1, 0, 1);
    MFMAS(af1, bf1);
  }
  {  // kt = 3 (cur=1), drain
    WAITVM(0); BAR();
    bf16x8 af0[8], bf0[4], af1[8], bf1[4];
    LOADFRAGS(af0, bf0, 1, 0);
    MFMAS(af0, bf0);
    LOADFRAGS(af1, bf1, 1, 1);
    MFMAS(af1, bf1);
  }
#undef STAGE
#undef LOADFRAGS
#undef MFMAS

  // exp(logits); logits in [-10,10] -> safe without max subtraction
  #pragma unroll
  for (int mi = 0; mi < 8; ++mi)
    #pragma unroll
    for (int ni = 0; ni < 4; ++ni)
      #pragma unroll
      for (int r = 0; r < 4; ++r)
        acc[mi][ni][r] = __expf(acc[mi][ni][r] * INV_T);

  // C/D layout: col = lane&15, row = (lane>>4)*4 + r
  // row partial sums over this wave's 64 cols -> slot (bn*4 + wn)
  #pragma unroll
  for (int mi = 0; mi < 8; ++mi)
    #pragma unroll
    for (int r = 0; r < 4; ++r) {
      float v = acc[mi][0][r] + acc[mi][1][r] + acc[mi][2][r] + acc[mi][3][r];
      v += __shfl_xor(v, 1); v += __shfl_xor(v, 2);
      v += __shfl_xor(v, 4); v += __shfl_xor(v, 8);
      if ((lane & 15) == 0)
        rowpart[(size_t)(bn * 4 + wn) * N + bm * 256 + wm * 128 + mi * 16 + (lane >> 4) * 4 + r] = v;
    }
  // col partial sums over this wave's 128 rows -> slot (bm*2 + wm)
  #pragma unroll
  for (int ni = 0; ni < 4; ++ni) {
    float v = 0.f;
    #pragma unroll
    for (int mi = 0; mi < 8; ++mi)
      #pragma unroll
      for (int r = 0; r < 4; ++r)
        v += acc[mi][ni][r];
    v += __shfl_xor(v, 16); v += __shfl_xor(v, 32);
    if (lane < 16)
      colpart[(size_t)(bm * 2 + wm) * N + bn * 256 + wn * 64 + ni * 16 + lane] = v;
  }
}

// Kernel 3: coalesced partial reduction (wave per slot residue, LDS combine).
__global__ __launch_bounds__(256) void reduce_kernel(
    const float* __restrict__ rowpart, const float* __restrict__ colpart,
    const float* __restrict__ diag, float* __restrict__ blocksum,
    int N, int NPr, int NPc) {
  __shared__ float redr[4][64], redc[4][64];
  int w = threadIdx.x >> 6, s = threadIdx.x & 63;
  int i = blockIdx.x * 64 + s;
  float rs = 0.f, cs = 0.f;
  for (int k = w; k < NPr; k += 4) rs += rowpart[(size_t)k * N + i];
  for (int k = w; k < NPc; k += 4) cs += colpart[(size_t)k * N + i];
  redr[w][s] = rs; redc[w][s] = cs;
  __syncthreads();
  if (w == 0) {
    float R = redr[0][s] + redr[1][s] + redr[2][s] + redr[3][s];
    float C = redc[0][s] + redc[1][s] + redc[2][s] + redc[3][s];
    float l = logf(R) + logf(C) - 2.0f * diag[i];
    #pragma unroll
    for (int m = 1; m < 64; m <<= 1) l += __shfl_xor(l, m);
    if (s == 0) blocksum[blockIdx.x] = l;
  }
}

// Kernel 4: final mean over 128 block sums
__global__ __launch_bounds__(128) void final_kernel(
    const float* __restrict__ blocksum, float* __restrict__ out, int N) {
  __shared__ float red[2];
  float v = blocksum[threadIdx.x];
  #pragma unroll
  for (int m = 1; m < 64; m <<= 1) v += __shfl_xor(v, m);
  if ((threadIdx.x & 63) == 0) red[threadIdx.x >> 6] = v;
  __syncthreads();
  if (threadIdx.x == 0) out[0] = (red[0] + red[1]) * (0.5f / (float)N);
}

extern "C" void kernel_launch(void* const* d_in, const int* in_sizes, int n_in,
                              void* d_out, int out_size, void* d_ws, size_t ws_size,
                              hipStream_t stream) {
  const float* images = (const float*)d_in[0];
  const float* captions = (const float*)d_in[1];
  int N = in_sizes[0] / D;   // 8192
  int NB = N / 256;          // 32 tile-blocks per dim
  int NPr = NB * 4;          // 128 row-partial slots
  int NPc = NB * 2;          // 64 col-partial slots
  char* w = (char*)d_ws;
  size_t off = 0;
  ushort* imn  = (ushort*)(w + off); off += (size_t)N * D * 2;
  ushort* capn = (ushort*)(w + off); off += (size_t)N * D * 2;
  float* diag    = (float*)(w + off); off += (size_t)N * 4;
  float* rowpart = (float*)(w + off); off += (size_t)NPr * N * 4;
  float* colpart = (float*)(w + off); off += (size_t)NPc * N * 4;
  float* blocksum = (float*)(w + off); off += 1024;
  float* out = (float*)d_out;

  normalize_kernel<<<N / 4, 256, 0, stream>>>(images, captions, imn, capn, diag, N);
  dim3 g(NB, NB);
  gemm_exp_kernel<<<g, 512, 0, stream>>>(imn, capn, rowpart, colpart, N);
  reduce_kernel<<<N / 64, 256, 0, stream>>>(rowpart, colpart, diag, blocksum, N, NPr, NPc);
  final_kernel<<<1, 128, 0, stream>>>(blocksum, out, N);
}

// Round 6
// 72.716 us; speedup vs baseline: 1.7102x; 1.0888x over previous
//
#include <hip/hip_runtime.h>
#include <hip/hip_bf16.h>

typedef short bf16x8 __attribute__((ext_vector_type(8)));
typedef float f32x4 __attribute__((ext_vector_type(4)));

typedef __attribute__((address_space(3))) void as3_void;
typedef const __attribute__((address_space(1))) void as1_void;

static constexpr int D = 256;
static constexpr float INV_T = 10.0f;  // 1 / 0.1

__device__ __forceinline__ ushort f2bf(float f) {
  union { float f; unsigned u; } v; v.f = f;
  unsigned r = v.u + 0x7fffu + ((v.u >> 16) & 1u);  // RNE
  return (ushort)(r >> 16);
}

// Kernel 1: L2-normalize rows of images & captions -> bf16; diag logits (fp32).
__global__ __launch_bounds__(256) void normalize_kernel(
    const float* __restrict__ im, const float* __restrict__ cap,
    ushort* __restrict__ imn, ushort* __restrict__ capn,
    float* __restrict__ diag, int N) {
  int tid = blockIdx.x * 256 + threadIdx.x;
  int w = tid >> 6;
  int lane = threadIdx.x & 63;
  if (w >= N) return;
  float4 vi = ((const float4*)(im + (size_t)w * D))[lane];
  float4 vc = ((const float4*)(cap + (size_t)w * D))[lane];
  float ssi = vi.x*vi.x + vi.y*vi.y + vi.z*vi.z + vi.w*vi.w;
  float ssc = vc.x*vc.x + vc.y*vc.y + vc.z*vc.z + vc.w*vc.w;
  #pragma unroll
  for (int m = 1; m < 64; m <<= 1) {
    ssi += __shfl_xor(ssi, m);
    ssc += __shfl_xor(ssc, m);
  }
  float ri = 1.0f / fmaxf(sqrtf(ssi), 1e-12f);
  float rc = 1.0f / fmaxf(sqrtf(ssc), 1e-12f);
  float ax = vi.x*ri, ay = vi.y*ri, az = vi.z*ri, aw = vi.w*ri;
  float cx = vc.x*rc, cy = vc.y*rc, cz = vc.z*rc, cw = vc.w*rc;
  ushort4 ua, uc;
  ua.x = f2bf(ax); ua.y = f2bf(ay); ua.z = f2bf(az); ua.w = f2bf(aw);
  uc.x = f2bf(cx); uc.y = f2bf(cy); uc.z = f2bf(cz); uc.w = f2bf(cw);
  ((ushort4*)(imn + (size_t)w * D))[lane] = ua;
  ((ushort4*)(capn + (size_t)w * D))[lane] = uc;
  float d = ax*cx + ay*cy + az*cz + aw*cw;
  #pragma unroll
  for (int m = 1; m < 64; m <<= 1) d += __shfl_xor(d, m);
  if (lane == 0) diag[w] = d * INV_T;
}

// Kernel 2: 256x256 tile, 8 waves (2M x 4N), BK=64, double-buffered LDS with
// the round-5-verified XOR swizzle (pre-swizzled global source + swizzled
// ds_read; 0 bank conflicts measured). NEW: 16-phase fine interleave -- each
// phase = {ds_read subtile (8 or 4 x b128) + stage issues; BAR; setprio(1);
// 16 MFMA; setprio(0); BAR}. Stage loads for kt+2 issued during kt+1
// (buffer freed by kt's exit); every kt-boundary wait is on loads issued
// >=2 phases earlier.
__global__ __launch_bounds__(512) void gemm_exp_kernel(
    const ushort* __restrict__ A, const ushort* __restrict__ Bm,
    float* __restrict__ rowpart, float* __restrict__ colpart, int N) {
  __shared__ ushort As[2][256 * 64];  // 2 x 32 KB
  __shared__ ushort Bs[2][256 * 64];  // 2 x 32 KB  (128 KB total)
  int bm = blockIdx.x, bn = blockIdx.y;
  int t = threadIdx.x;
  int lane = t & 63;
  int wv = t >> 6;             // 0..7
  int wm = wv >> 2;            // 0..1 : rows [wm*128, +128)
  int wn = wv & 3;             // 0..3 : cols [wn*64, +64)

  // staging: lane writes LDS slot row = q*64 + wv*8 + (lane>>3),
  // col' = (lane&7)*8; global source col pre-swizzled col = col' ^ ((row&7)*8)
  int srow = wv * 8 + (lane >> 3);
  int scol = (((lane & 7) ^ (lane >> 3)) * 8);
  const ushort* agbase = A + ((size_t)bm * 256 + srow) * D + scol;
  const ushort* bgbase = Bm + ((size_t)bn * 256 + srow) * D + scol;

  f32x4 acc[8][4];
  #pragma unroll
  for (int mi = 0; mi < 8; ++mi)
    #pragma unroll
    for (int ni = 0; ni < 4; ++ni)
      acc[mi][ni] = (f32x4){0.f, 0.f, 0.f, 0.f};

  int rb = lane & 15;
  int kb = (lane >> 4) * 8;
  int rb7s = (rb & 7) * 8;     // read-side swizzle term (elem units)

#define VMWAIT(n) asm volatile("s_waitcnt vmcnt(" #n ")" ::: "memory")
#define BARRIER() asm volatile("s_barrier" ::: "memory")

  // stage quantum q: rows [q*64, q*64+64) of A and B for K-tile kt (2 loads)
#define STAGEQ(buf, kt, q)                                                   \
  __builtin_amdgcn_global_load_lds(                                          \
      (as1_void*)(agbase + (size_t)(q) * 64 * D + (kt) * 64),                \
      (as3_void*)(&As[buf][(q) * 4096 + wv * 512]), 16, 0, 0);               \
  __builtin_amdgcn_global_load_lds(                                          \
      (as1_void*)(bgbase + (size_t)(q) * 64 * D + (kt) * 64),                \
      (as3_void*)(&Bs[buf][(q) * 4096 + wv * 512]), 16, 0, 0);

#define READ_B(BF, cur, ks)                                                  \
  { int cc = ((ks) * 32 + kb) ^ rb7s;                                        \
    _Pragma("unroll") for (int ni = 0; ni < 4; ++ni)                         \
      BF[ni] = *(const bf16x8*)(&Bs[cur][(wn * 64 + ni * 16 + rb) * 64 + cc]); }

#define READ_A(AF, cur, ks, mh)                                              \
  { int cc = ((ks) * 32 + kb) ^ rb7s;                                        \
    _Pragma("unroll") for (int mi = 0; mi < 4; ++mi)                         \
      AF[mi] = *(const bf16x8*)(&As[cur][(wm * 128 + ((mh) * 4 + mi) * 16 + rb) * 64 + cc]); }

#define MF16(AF, BF, mh)                                                     \
  { __builtin_amdgcn_s_setprio(1);                                           \
    _Pragma("unroll") for (int mi = 0; mi < 4; ++mi)                         \
      _Pragma("unroll") for (int ni = 0; ni < 4; ++ni)                       \
        acc[(mh) * 4 + mi][ni] = __builtin_amdgcn_mfma_f32_16x16x32_bf16(    \
            AF[mi], BF[ni], acc[(mh) * 4 + mi][ni], 0, 0, 0);                \
    __builtin_amdgcn_s_setprio(0); }

  // 4 phases per K-tile: (ks0,mlo)(ks0,mhi)(ks1,mlo)(ks1,mhi); B-frags reused
  // across the two mh phases of each ks. S1/S2 = stage-issue slots.
#define KT_BODY(cur, S1, S2)                                                 \
  {                                                                          \
    bf16x8 a0[4], a1[4], b0[4], b1[4];                                       \
    READ_B(b0, cur, 0); READ_A(a0, cur, 0, 0);                               \
    S1;                                                                      \
    BARRIER();                                                               \
    MF16(a0, b0, 0);                                                         \
    BARRIER();                                                               \
    READ_A(a1, cur, 0, 1);                                                   \
    S2;                                                                      \
    BARRIER();                                                               \
    MF16(a1, b0, 1);                                                         \
    BARRIER();                                                               \
    READ_B(b1, cur, 1); READ_A(a0, cur, 1, 0);                               \
    BARRIER();                                                               \
    MF16(a0, b1, 0);                                                         \
    BARRIER();                                                               \
    READ_A(a1, cur, 1, 1);                                                   \
    BARRIER();                                                               \
    MF16(a1, b1, 1);                                                         \
    BARRIER();                                                               \
  }

  // Prologue: stage kt0 -> buf0 (8 oldest loads), kt1 -> buf1
  STAGEQ(0, 0, 0) STAGEQ(0, 0, 1) STAGEQ(0, 0, 2) STAGEQ(0, 0, 3)
  STAGEQ(1, 1, 0) STAGEQ(1, 1, 1) STAGEQ(1, 1, 2) STAGEQ(1, 1, 3)

  VMWAIT(8); BARRIER();                        // kt0 resident (kt1 in flight)
  KT_BODY(0, , )
  VMWAIT(0); BARRIER();                        // kt1 resident
  KT_BODY(1, STAGEQ(0, 2, 0) STAGEQ(0, 2, 1), STAGEQ(0, 2, 2) STAGEQ(0, 2, 3))
  VMWAIT(0); BARRIER();                        // kt2 resident (issued >=6 phases ago)
  KT_BODY(0, STAGEQ(1, 3, 0) STAGEQ(1, 3, 1), STAGEQ(1, 3, 2) STAGEQ(1, 3, 3))
  VMWAIT(0); BARRIER();                        // kt3 resident
  KT_BODY(1, , )

#undef KT_BODY
#undef MF16
#undef READ_A
#undef READ_B
#undef STAGEQ

  // exp(logits); logits in [-10,10] -> safe without max subtraction
  #pragma unroll
  for (int mi = 0; mi < 8; ++mi)
    #pragma unroll
    for (int ni = 0; ni < 4; ++ni)
      #pragma unroll
      for (int r = 0; r < 4; ++r)
        acc[mi][ni][r] = __expf(acc[mi][ni][r] * INV_T);

  // C/D layout: col = lane&15, row = (lane>>4)*4 + r
  // Row sums via packed 4-value butterfly: 5 shuffles per mi (vs 16 naive).
  // After the 4 xor-steps, lane l holds the full 16-lane sum for r = l&3,
  // row = (l>>4)*4 + (l&3), duplicated over bits 2-3 of lane.
  bool sb0 = (lane & 1) != 0;
  bool sb1 = (lane & 2) != 0;
  #pragma unroll
  for (int mi = 0; mi < 8; ++mi) {
    float v0 = acc[mi][0][0] + acc[mi][1][0] + acc[mi][2][0] + acc[mi][3][0];
    float v1 = acc[mi][0][1] + acc[mi][1][1] + acc[mi][2][1] + acc[mi][3][1];
    float v2 = acc[mi][0][2] + acc[mi][1][2] + acc[mi][2][2] + acc[mi][3][2];
    float v3 = acc[mi][0][3] + acc[mi][1][3] + acc[mi][2][3] + acc[mi][3][3];
    float h0 = (sb0 ? v1 : v0) + __shfl_xor(sb0 ? v0 : v1, 1);
    float h1 = (sb0 ? v3 : v2) + __shfl_xor(sb0 ? v2 : v3, 1);
    float g  = (sb1 ? h1 : h0) + __shfl_xor(sb1 ? h0 : h1, 2);
    g += __shfl_xor(g, 4);
    g += __shfl_xor(g, 8);
    if ((lane & 12) == 0)
      rowpart[(size_t)(bn * 4 + wn) * N + bm * 256 + wm * 128 + mi * 16 +
              (lane >> 4) * 4 + (lane & 3)] = g;
  }
  // col partial sums over this wave's 128 rows -> slot (bm*2 + wm)
  #pragma unroll
  for (int ni = 0; ni < 4; ++ni) {
    float v = 0.f;
    #pragma unroll
    for (int mi = 0; mi < 8; ++mi)
      #pragma unroll
      for (int r = 0; r < 4; ++r)
        v += acc[mi][ni][r];
    v += __shfl_xor(v, 16); v += __shfl_xor(v, 32);
    if (lane < 16)
      colpart[(size_t)(bm * 2 + wm) * N + bn * 256 + wn * 64 + ni * 16 + lane] = v;
  }
#undef VMWAIT
#undef BARRIER
}

// Kernel 3: coalesced partial reduction (wave per slot residue, LDS combine).
__global__ __launch_bounds__(256) void reduce_kernel(
    const float* __restrict__ rowpart, const float* __restrict__ colpart,
    const float* __restrict__ diag, float* __restrict__ blocksum,
    int N, int NPr, int NPc) {
  __shared__ float redr[4][64], redc[4][64];
  int w = threadIdx.x >> 6, s = threadIdx.x & 63;
  int i = blockIdx.x * 64 + s;
  float rs = 0.f, cs = 0.f;
  for (int k = w; k < NPr; k += 4) rs += rowpart[(size_t)k * N + i];
  for (int k = w; k < NPc; k += 4) cs += colpart[(size_t)k * N + i];
  redr[w][s] = rs; redc[w][s] = cs;
  __syncthreads();
  if (w == 0) {
    float R = redr[0][s] + redr[1][s] + redr[2][s] + redr[3][s];
    float C = redc[0][s] + redc[1][s] + redc[2][s] + redc[3][s];
    float l = logf(R) + logf(C) - 2.0f * diag[i];
    #pragma unroll
    for (int m = 1; m < 64; m <<= 1) l += __shfl_xor(l, m);
    if (s == 0) blocksum[blockIdx.x] = l;
  }
}

// Kernel 4: final mean over 128 block sums
__global__ __launch_bounds__(128) void final_kernel(
    const float* __restrict__ blocksum, float* __restrict__ out, int N) {
  __shared__ float red[2];
  float v = blocksum[threadIdx.x];
  #pragma unroll
  for (int m = 1; m < 64; m <<= 1) v += __shfl_xor(v, m);
  if ((threadIdx.x & 63) == 0) red[threadIdx.x >> 6] = v;
  __syncthreads();
  if (threadIdx.x == 0) out[0] = (red[0] + red[1]) * (0.5f / (float)N);
}

extern "C" void kernel_launch(void* const* d_in, const int* in_sizes, int n_in,
                              void* d_out, int out_size, void* d_ws, size_t ws_size,
                              hipStream_t stream) {
  const float* images = (const float*)d_in[0];
  const float* captions = (const float*)d_in[1];
  int N = in_sizes[0] / D;   // 8192
  int NB = N / 256;          // 32 tile-blocks per dim
  int NPr = NB * 4;          // 128 row-partial slots
  int NPc = NB * 2;          // 64 col-partial slots
  char* w = (char*)d_ws;
  size_t off = 0;
  ushort* imn  = (ushort*)(w + off); off += (size_t)N * D * 2;
  ushort* capn = (ushort*)(w + off); off += (size_t)N * D * 2;
  float* diag    = (float*)(w + off); off += (size_t)N * 4;
  float* rowpart = (float*)(w + off); off += (size_t)NPr * N * 4;
  float* colpart = (float*)(w + off); off += (size_t)NPc * N * 4;
  float* blocksum = (float*)(w + off); off += 1024;
  float* out = (float*)d_out;

  normalize_kernel<<<N / 4, 256, 0, stream>>>(images, captions, imn, capn, diag, N);
  dim3 g(NB, NB);
  gemm_exp_kernel<<<g, 512, 0, stream>>>(imn, capn, rowpart, colpart, N);
  reduce_kernel<<<N / 64, 256, 0, stream>>>(rowpart, colpart, diag, blocksum, N, NPr, NPc);
  final_kernel<<<1, 128, 0, stream>>>(blocksum, out, N);
}